// Round 4
// 323.134 us; speedup vs baseline: 1.0002x; 1.0002x over previous
//
#include <hip/hip_runtime.h>

#define BSZ 8
#define SEQ 16
#define DIMN 512
#define SP 4096
#define KVL 4112

#define SCALE 0.0625f   // (512/2)^-0.5

// workspace layout (float offsets)
#define PPART 0                      // 3 * 4 * 128 * 512 = 786432
#define QBUF  786432                 // 65536
#define KNEW  851968                 // 65536
#define VNEW  917504                 // 65536
#define PROBS 983040                 // 8*16*4112 = 526336
#define APART 1509376                // 65 * 65536 = 4259840
#define ATTEN 5769216                // 65536
#define OPART 5834752                // 4 * 65536 = 262144

// ---------------------------------------------------------------------------
// Kernel A: partial projection  out[row][e] += sum_{d in dt-range} X[row][d]*W[e][d]
// grid (8b*4et, 4dt, nm), block 64.  Thread owns 8 rows x 4 e-cols over 128 d.
// ---------------------------------------------------------------------------
__global__ __launch_bounds__(64) void proj_partial(
    const float* __restrict__ X, const float* __restrict__ W0,
    const float* __restrict__ W1, const float* __restrict__ W2,
    float* __restrict__ outbase)
{
  __shared__ float xs[SEQ][128];
  int b = blockIdx.x >> 2, et = blockIdx.x & 3;
  int dt = blockIdx.y, m = blockIdx.z;
  const float* W = (m == 0) ? W0 : (m == 1) ? W1 : W2;
  float* outp = outbase + (size_t)m * (4 * 65536) + (size_t)dt * 65536;
  int t = threadIdx.x;

  const float4* xsrc = (const float4*)(X + (size_t)(b * SEQ) * DIMN + dt * 128);
  for (int i = t; i < SEQ * 32; i += 64) {
    int row = i >> 5, j = i & 31;
    *(float4*)&xs[row][j * 4] = xsrc[row * 128 + j];
  }
  __syncthreads();

  int r0 = (t >> 5) * 8;
  int e = et * 128 + (t & 31) * 4;
  float acc[8][4];
#pragma unroll
  for (int r = 0; r < 8; ++r)
#pragma unroll
    for (int i = 0; i < 4; ++i) acc[r][i] = 0.f;

  const float* wbase = W + dt * 128;
  for (int d4 = 0; d4 < 32; ++d4) {
    float4 w[4];
#pragma unroll
    for (int i = 0; i < 4; ++i)
      w[i] = *(const float4*)(wbase + (size_t)(e + i) * DIMN + d4 * 4);
#pragma unroll
    for (int r = 0; r < 8; ++r) {
      float4 xv = *(const float4*)&xs[r0 + r][d4 * 4];
#pragma unroll
      for (int i = 0; i < 4; ++i)
        acc[r][i] += xv.x * w[i].x + xv.y * w[i].y + xv.z * w[i].z + xv.w * w[i].w;
    }
  }
#pragma unroll
  for (int r = 0; r < 8; ++r) {
    float4 o = make_float4(acc[r][0], acc[r][1], acc[r][2], acc[r][3]);
    *(float4*)(outp + (size_t)(b * SEQ + r0 + r) * DIMN + e) = o;
  }
}

// ---------------------------------------------------------------------------
// Kernel B: reduce 4 d-partials.  src layout [m][dt][65536], dst [m*65536+j]
// ---------------------------------------------------------------------------
__global__ __launch_bounds__(256) void reduce_dt(
    const float* __restrict__ src, float* __restrict__ dst, int nm)
{
  int idx = blockIdx.x * 256 + threadIdx.x;
  if (idx >= nm * 65536) return;
  int m = idx >> 16, j = idx & 65535;
  const float* s = src + (size_t)m * (4 * 65536);
  dst[idx] = s[j] + s[65536 + j] + s[2 * 65536 + j] + s[3 * 65536 + j];
}

// ---------------------------------------------------------------------------
// Kernel C: scores.  One wave per position; lane holds q[.., lane*8..lane*8+7]
// for all 16 queries in regs; tree cross-lane reduction (ownership halving).
// grid (8, 65 chunks of 64 pos), block 256 (4 waves, interleaved positions).
// ---------------------------------------------------------------------------
__global__ __launch_bounds__(256) void scores_kernel(
    const float* __restrict__ qbuf, const float* __restrict__ cache_k,
    const float* __restrict__ knew, float* __restrict__ weight)
{
  int b = blockIdx.x;
  int p0 = blockIdx.y * 64;
  int len = KVL - p0; if (len > 64) len = 64;
  int t = threadIdx.x, lane = t & 63, w = t >> 6;

  float4 qa[SEQ], qb[SEQ];
  const float* qbase = qbuf + (size_t)b * SEQ * DIMN + lane * 8;
#pragma unroll
  for (int s = 0; s < SEQ; ++s) {
    qa[s] = *(const float4*)(qbase + s * DIMN);
    qb[s] = *(const float4*)(qbase + s * DIMN + 4);
  }

  bool b1 = (lane & 1), b2 = (lane & 2), b4 = (lane & 4), b8 = (lane & 8);
  int niter = (len - w + 3) >> 2;   // positions p0 + w + 4*i
#pragma unroll 2
  for (int i = 0; i < niter; ++i) {
    int p = p0 + w + 4 * i;
    const float* krow = (p < SP)
        ? (cache_k + ((size_t)b * 8192 + p) * DIMN)
        : (knew + (size_t)(b * SEQ + (p - SP)) * DIMN);
    float4 ka = *(const float4*)(krow + lane * 8);
    float4 kb = *(const float4*)(krow + lane * 8 + 4);

    float acc[SEQ];
#pragma unroll
    for (int s = 0; s < SEQ; ++s) {
      acc[s] = qa[s].x * ka.x + qa[s].y * ka.y + qa[s].z * ka.z + qa[s].w * ka.w
             + qb[s].x * kb.x + qb[s].y * kb.y + qb[s].z * kb.z + qb[s].w * kb.w;
    }
    // tree reduction: halve owned set each stage, exchange non-kept half
    float r8[8];
#pragma unroll
    for (int u = 0; u < 8; ++u) {
      float keep = b1 ? acc[u + 8] : acc[u];
      float send = b1 ? acc[u] : acc[u + 8];
      r8[u] = keep + __shfl_xor(send, 1);
    }
    float r4[4];
#pragma unroll
    for (int u = 0; u < 4; ++u) {
      float keep = b2 ? r8[u + 4] : r8[u];
      float send = b2 ? r8[u] : r8[u + 4];
      r4[u] = keep + __shfl_xor(send, 2);
    }
    float r2[2];
#pragma unroll
    for (int u = 0; u < 2; ++u) {
      float keep = b4 ? r4[u + 2] : r4[u];
      float send = b4 ? r4[u] : r4[u + 2];
      r2[u] = keep + __shfl_xor(send, 4);
    }
    float keep = b8 ? r2[1] : r2[0];
    float send = b8 ? r2[0] : r2[1];
    float r1 = keep + __shfl_xor(send, 8);
    r1 += __shfl_xor(r1, 16);
    r1 += __shfl_xor(r1, 32);

    if (lane < 16) {
      int s = ((lane & 1) << 3) | ((lane & 2) << 1) | ((lane & 4) >> 1) | ((lane & 8) >> 3);
      weight[(size_t)(b * SEQ + s) * KVL + p] = r1 * SCALE;
    }
  }
}

// ---------------------------------------------------------------------------
// Kernel D: softmax over KVL per (b,s) row.  probs = softmax(weight + mask)
// ---------------------------------------------------------------------------
__global__ __launch_bounds__(256) void softmax_kernel(
    const float* __restrict__ weight, const float* __restrict__ mask,
    float* __restrict__ probs)
{
  int row = blockIdx.x;          // b*16 + s
  int s = row & 15;
  int t = threadIdx.x, lane = t & 63, w = t >> 6;
  const float* src = weight + (size_t)row * KVL;
  const float* msk = mask + (size_t)s * KVL;

  float vals[17];
  float mx = -1e30f;
#pragma unroll
  for (int i = 0; i < 17; ++i) {
    int p = t + i * 256;
    if (p < KVL) { vals[i] = src[p] + msk[p]; mx = fmaxf(mx, vals[i]); }
    else vals[i] = -1e30f;
  }
  for (int off = 32; off >= 1; off >>= 1) mx = fmaxf(mx, __shfl_xor(mx, off));
  __shared__ float redm[4], reds[4];
  if (lane == 0) redm[w] = mx;
  __syncthreads();
  mx = fmaxf(fmaxf(redm[0], redm[1]), fmaxf(redm[2], redm[3]));

  float sum = 0.f;
#pragma unroll
  for (int i = 0; i < 17; ++i) {
    int p = t + i * 256;
    if (p < KVL) { vals[i] = __expf(vals[i] - mx); sum += vals[i]; }
  }
  for (int off = 32; off >= 1; off >>= 1) sum += __shfl_xor(sum, off);
  if (lane == 0) reds[w] = sum;
  __syncthreads();
  sum = reds[0] + reds[1] + reds[2] + reds[3];
  float inv = 1.0f / sum;

  float* dst = probs + (size_t)row * KVL;
#pragma unroll
  for (int i = 0; i < 17; ++i) {
    int p = t + i * 256;
    if (p < KVL) dst[p] = vals[i] * inv;
  }
}

// ---------------------------------------------------------------------------
// Kernel E: atten partials.  grid (8, 65 chunks of 64 pos), block 256.
// Thread owns v-cols {t, t+256} for all 16 queries; probs chunk staged in LDS.
// ---------------------------------------------------------------------------
__global__ __launch_bounds__(256) void attnv_kernel(
    const float* __restrict__ probs, const float* __restrict__ cache_v,
    const float* __restrict__ vnew, float* __restrict__ apart)
{
  __shared__ float pl[SEQ][64];
  int b = blockIdx.x, c = blockIdx.y;
  int p0 = c * 64;
  int len = KVL - p0; if (len > 64) len = 64;
  int t = threadIdx.x;

  for (int i = t; i < SEQ * 64; i += 256) {
    int q = i >> 6, j = i & 63;
    pl[q][j] = (j < len) ? probs[(size_t)(b * SEQ + q) * KVL + p0 + j] : 0.f;
  }
  __syncthreads();

  float acc0[SEQ], acc1[SEQ];
#pragma unroll
  for (int q = 0; q < SEQ; ++q) { acc0[q] = 0.f; acc1[q] = 0.f; }

  int nj4 = len >> 2;   // 16 or 4
  for (int j4 = 0; j4 < nj4; ++j4) {
    float4 pv[SEQ];
#pragma unroll
    for (int q = 0; q < SEQ; ++q) pv[q] = *(const float4*)&pl[q][j4 * 4];
#pragma unroll
    for (int jj = 0; jj < 4; ++jj) {
      int p = p0 + j4 * 4 + jj;
      const float* vrow = (p < SP)
          ? (cache_v + ((size_t)b * 8192 + p) * DIMN)
          : (vnew + (size_t)(b * SEQ + (p - SP)) * DIMN);
      float va = vrow[t], vb = vrow[t + 256];
#pragma unroll
      for (int q = 0; q < SEQ; ++q) {
        float pj = (jj == 0) ? pv[q].x : (jj == 1) ? pv[q].y : (jj == 2) ? pv[q].z : pv[q].w;
        acc0[q] += pj * va;
        acc1[q] += pj * vb;
      }
    }
  }
  float* outp = apart + (size_t)c * 65536 + (size_t)b * SEQ * DIMN;
#pragma unroll
  for (int q = 0; q < SEQ; ++q) {
    outp[q * DIMN + t] = acc0[q];
    outp[q * DIMN + t + 256] = acc1[q];
  }
}

// ---------------------------------------------------------------------------
// Kernel F: reduce 65 position-chunk partials -> atten
// ---------------------------------------------------------------------------
__global__ __launch_bounds__(256) void reduce_att(
    const float* __restrict__ apart, float* __restrict__ atten)
{
  int idx = blockIdx.x * 256 + threadIdx.x;   // grid 256 -> 65536
  float s = 0.f;
  for (int c = 0; c < 65; ++c) s += apart[(size_t)c * 65536 + idx];
  atten[idx] = s;
}

// ---------------------------------------------------------------------------
extern "C" void kernel_launch(void* const* d_in, const int* in_sizes, int n_in,
                              void* d_out, int out_size, void* d_ws, size_t ws_size,
                              hipStream_t stream) {
  const float* x       = (const float*)d_in[0];
  // d_in[1] = start_pos (fixed 4096, baked into constants)
  const float* mask    = (const float*)d_in[2];
  const float* Wq      = (const float*)d_in[3];
  const float* Wk      = (const float*)d_in[4];
  const float* Wv      = (const float*)d_in[5];
  const float* Wo      = (const float*)d_in[6];
  const float* cache_k = (const float*)d_in[7];
  const float* cache_v = (const float*)d_in[8];
  float* out    = (float*)d_out;           // [8,16,512]
  float* weight = out + 65536;             // [8,16,4112]
  float* ws     = (float*)d_ws;

  // q/k/v projections (split-K partials, then reduce)
  proj_partial<<<dim3(32, 4, 3), 64, 0, stream>>>(x, Wq, Wk, Wv, ws + PPART);
  reduce_dt<<<dim3(768), 256, 0, stream>>>(ws + PPART, ws + QBUF, 3);
  // scores -> weight output (pre-mask, scaled)
  scores_kernel<<<dim3(8, 65), 256, 0, stream>>>(ws + QBUF, cache_k, ws + KNEW, weight);
  // softmax(weight + mask) -> probs
  softmax_kernel<<<dim3(128), 256, 0, stream>>>(weight, mask, ws + PROBS);
  // probs @ v_full (split over position chunks)
  attnv_kernel<<<dim3(8, 65), 256, 0, stream>>>(ws + PROBS, cache_v, ws + VNEW, ws + APART);
  reduce_att<<<dim3(256), 256, 0, stream>>>(ws + APART, ws + ATTEN);
  // output projection
  proj_partial<<<dim3(32, 4, 1), 64, 0, stream>>>(ws + ATTEN, Wo, Wo, Wo, ws + OPART);
  reduce_dt<<<dim3(256), 256, 0, stream>>>(ws + OPART, out, 1);
}

// Round 5
// 310.018 us; speedup vs baseline: 1.0425x; 1.0423x over previous
//
#include <hip/hip_runtime.h>

#define BSZ 8
#define SEQ 16
#define DIMN 512
#define SP 4096
#define KVL 4112

#define SCALE 0.0625f   // (512/2)^-0.5

// workspace layout (float offsets)
#define QBUF  0          // 65536
#define KNEW  65536      // 65536
#define VNEW  131072     // 65536
#define PROBS 196608     // 8*16*4112 = 526336
#define APART 722944     // 65 * 65536 = 4259840
#define ATTEN 4982784    // 65536

// ---------------------------------------------------------------------------
// 16-value cross-lane tree reduction (ownership halving). Each lane enters
// with acc[16] = partial dots over its 8 k-elements; lanes 0..15 exit with
// the full dot for row s = bitrev4(lane). Verified in scores_kernel.
// ---------------------------------------------------------------------------
__device__ __forceinline__ float tree16(const float* acc, bool b1, bool b2, bool b4, bool b8)
{
  float r8[8];
#pragma unroll
  for (int u = 0; u < 8; ++u) {
    float keep = b1 ? acc[u + 8] : acc[u];
    float send = b1 ? acc[u] : acc[u + 8];
    r8[u] = keep + __shfl_xor(send, 1);
  }
  float r4[4];
#pragma unroll
  for (int u = 0; u < 4; ++u) {
    float keep = b2 ? r8[u + 4] : r8[u];
    float send = b2 ? r8[u] : r8[u + 4];
    r4[u] = keep + __shfl_xor(send, 2);
  }
  float r2[2];
#pragma unroll
  for (int u = 0; u < 2; ++u) {
    float keep = b4 ? r4[u + 2] : r4[u];
    float send = b4 ? r4[u] : r4[u + 2];
    r2[u] = keep + __shfl_xor(send, 4);
  }
  float keep = b8 ? r2[1] : r2[0];
  float send = b8 ? r2[0] : r2[1];
  float r1 = keep + __shfl_xor(send, 8);
  r1 += __shfl_xor(r1, 16);
  r1 += __shfl_xor(r1, 32);
  return r1;
}

// ---------------------------------------------------------------------------
// Kernel 1/6: projection, dot-product style (full K, no split-K reduce).
// Wave holds 16 X-rows of one b in regs (lane owns 8 floats/row); streams
// W-rows with coalesced 2KB/wave loads. grid (8 b, ncols/32), block 256.
// Wave w handles cols e = by*32 + w + 4*i, i<8.  e>=512 selects W1/W2
// (QKV concat); out-proj launches 16 col-chunks so m==0 on every path.
// ---------------------------------------------------------------------------
__global__ __launch_bounds__(256) void proj_dot(
    const float* __restrict__ X,
    const float* __restrict__ W0, const float* __restrict__ W1,
    const float* __restrict__ W2,
    float* __restrict__ D0, float* __restrict__ D1, float* __restrict__ D2)
{
  int b = blockIdx.x;
  int e0 = blockIdx.y * 32;
  int t = threadIdx.x, lane = t & 63, w = t >> 6;

  float4 xa[SEQ], xb[SEQ];
  const float* xbase = X + (size_t)b * SEQ * DIMN + lane * 8;
#pragma unroll
  for (int s = 0; s < SEQ; ++s) {
    xa[s] = *(const float4*)(xbase + s * DIMN);
    xb[s] = *(const float4*)(xbase + s * DIMN + 4);
  }

  bool b1 = (lane & 1), b2 = (lane & 2), b4 = (lane & 4), b8 = (lane & 8);
#pragma unroll 2
  for (int i = 0; i < 8; ++i) {
    int e = e0 + w + 4 * i;              // wave-uniform
    int m = e >> 9, col = e & 511;
    const float* W = (m == 0) ? W0 : (m == 1) ? W1 : W2;
    const float* wrow = W + (size_t)col * DIMN + lane * 8;
    float4 ka = *(const float4*)(wrow);
    float4 kb = *(const float4*)(wrow + 4);

    float acc[SEQ];
#pragma unroll
    for (int s = 0; s < SEQ; ++s) {
      acc[s] = xa[s].x * ka.x + xa[s].y * ka.y + xa[s].z * ka.z + xa[s].w * ka.w
             + xb[s].x * kb.x + xb[s].y * kb.y + xb[s].z * kb.z + xb[s].w * kb.w;
    }
    float r1 = tree16(acc, b1, b2, b4, b8);
    if (lane < 16) {
      int s = ((lane & 1) << 3) | ((lane & 2) << 1) | ((lane & 4) >> 1) | ((lane & 8) >> 3);
      float* D = (m == 0) ? D0 : (m == 1) ? D1 : D2;
      D[(size_t)(b * SEQ + s) * DIMN + col] = r1;
    }
  }
}

// ---------------------------------------------------------------------------
// Kernel 2/6: scores.  One wave per position; lane holds q[.., lane*8..+7]
// for all 16 queries in regs; tree cross-lane reduction.  (verified)
// grid (8, 65 chunks of 64 pos), block 256 (4 waves, interleaved positions).
// ---------------------------------------------------------------------------
__global__ __launch_bounds__(256) void scores_kernel(
    const float* __restrict__ qbuf, const float* __restrict__ cache_k,
    const float* __restrict__ knew, float* __restrict__ weight)
{
  int b = blockIdx.x;
  int p0 = blockIdx.y * 64;
  int len = KVL - p0; if (len > 64) len = 64;
  int t = threadIdx.x, lane = t & 63, w = t >> 6;

  float4 qa[SEQ], qb[SEQ];
  const float* qbase = qbuf + (size_t)b * SEQ * DIMN + lane * 8;
#pragma unroll
  for (int s = 0; s < SEQ; ++s) {
    qa[s] = *(const float4*)(qbase + s * DIMN);
    qb[s] = *(const float4*)(qbase + s * DIMN + 4);
  }

  bool b1 = (lane & 1), b2 = (lane & 2), b4 = (lane & 4), b8 = (lane & 8);
  int niter = (len - w + 3) >> 2;   // positions p0 + w + 4*i
#pragma unroll 2
  for (int i = 0; i < niter; ++i) {
    int p = p0 + w + 4 * i;
    const float* krow = (p < SP)
        ? (cache_k + ((size_t)b * 8192 + p) * DIMN)
        : (knew + (size_t)(b * SEQ + (p - SP)) * DIMN);
    float4 ka = *(const float4*)(krow + lane * 8);
    float4 kb = *(const float4*)(krow + lane * 8 + 4);

    float acc[SEQ];
#pragma unroll
    for (int s = 0; s < SEQ; ++s) {
      acc[s] = qa[s].x * ka.x + qa[s].y * ka.y + qa[s].z * ka.z + qa[s].w * ka.w
             + qb[s].x * kb.x + qb[s].y * kb.y + qb[s].z * kb.z + qb[s].w * kb.w;
    }
    float r1 = tree16(acc, b1, b2, b4, b8);
    if (lane < 16) {
      int s = ((lane & 1) << 3) | ((lane & 2) << 1) | ((lane & 4) >> 1) | ((lane & 8) >> 3);
      weight[(size_t)(b * SEQ + s) * KVL + p] = r1 * SCALE;
    }
  }
}

// ---------------------------------------------------------------------------
// Kernel 3/6: softmax over KVL per (b,s) row.  probs = softmax(weight + mask)
// (verified)
// ---------------------------------------------------------------------------
__global__ __launch_bounds__(256) void softmax_kernel(
    const float* __restrict__ weight, const float* __restrict__ mask,
    float* __restrict__ probs)
{
  int row = blockIdx.x;          // b*16 + s
  int s = row & 15;
  int t = threadIdx.x, lane = t & 63, w = t >> 6;
  const float* src = weight + (size_t)row * KVL;
  const float* msk = mask + (size_t)s * KVL;

  float vals[17];
  float mx = -1e30f;
#pragma unroll
  for (int i = 0; i < 17; ++i) {
    int p = t + i * 256;
    if (p < KVL) { vals[i] = src[p] + msk[p]; mx = fmaxf(mx, vals[i]); }
    else vals[i] = -1e30f;
  }
  for (int off = 32; off >= 1; off >>= 1) mx = fmaxf(mx, __shfl_xor(mx, off));
  __shared__ float redm[4], reds[4];
  if (lane == 0) redm[w] = mx;
  __syncthreads();
  mx = fmaxf(fmaxf(redm[0], redm[1]), fmaxf(redm[2], redm[3]));

  float sum = 0.f;
#pragma unroll
  for (int i = 0; i < 17; ++i) {
    int p = t + i * 256;
    if (p < KVL) { vals[i] = __expf(vals[i] - mx); sum += vals[i]; }
  }
  for (int off = 32; off >= 1; off >>= 1) sum += __shfl_xor(sum, off);
  if (lane == 0) reds[w] = sum;
  __syncthreads();
  sum = reds[0] + reds[1] + reds[2] + reds[3];
  float inv = 1.0f / sum;

  float* dst = probs + (size_t)row * KVL;
#pragma unroll
  for (int i = 0; i < 17; ++i) {
    int p = t + i * 256;
    if (p < KVL) dst[p] = vals[i] * inv;
  }
}

// ---------------------------------------------------------------------------
// Kernel 4/6: atten partials.  grid (8, 65 chunks of 64 pos), block 256.
// Thread owns v-cols {t, t+256} for all 16 queries; probs chunk staged in LDS.
// (verified)
// ---------------------------------------------------------------------------
__global__ __launch_bounds__(256) void attnv_kernel(
    const float* __restrict__ probs, const float* __restrict__ cache_v,
    const float* __restrict__ vnew, float* __restrict__ apart)
{
  __shared__ float pl[SEQ][64];
  int b = blockIdx.x, c = blockIdx.y;
  int p0 = c * 64;
  int len = KVL - p0; if (len > 64) len = 64;
  int t = threadIdx.x;

  for (int i = t; i < SEQ * 64; i += 256) {
    int q = i >> 6, j = i & 63;
    pl[q][j] = (j < len) ? probs[(size_t)(b * SEQ + q) * KVL + p0 + j] : 0.f;
  }
  __syncthreads();

  float acc0[SEQ], acc1[SEQ];
#pragma unroll
  for (int q = 0; q < SEQ; ++q) { acc0[q] = 0.f; acc1[q] = 0.f; }

  int nj4 = len >> 2;   // 16 or 4
  for (int j4 = 0; j4 < nj4; ++j4) {
    float4 pv[SEQ];
#pragma unroll
    for (int q = 0; q < SEQ; ++q) pv[q] = *(const float4*)&pl[q][j4 * 4];
#pragma unroll
    for (int jj = 0; jj < 4; ++jj) {
      int p = p0 + j4 * 4 + jj;
      const float* vrow = (p < SP)
          ? (cache_v + ((size_t)b * 8192 + p) * DIMN)
          : (vnew + (size_t)(b * SEQ + (p - SP)) * DIMN);
      float va = vrow[t], vb = vrow[t + 256];
#pragma unroll
      for (int q = 0; q < SEQ; ++q) {
        float pj = (jj == 0) ? pv[q].x : (jj == 1) ? pv[q].y : (jj == 2) ? pv[q].z : pv[q].w;
        acc0[q] += pj * va;
        acc1[q] += pj * vb;
      }
    }
  }
  float* outp = apart + (size_t)c * 65536 + (size_t)b * SEQ * DIMN;
#pragma unroll
  for (int q = 0; q < SEQ; ++q) {
    outp[q * DIMN + t] = acc0[q];
    outp[q * DIMN + t + 256] = acc1[q];
  }
}

// ---------------------------------------------------------------------------
// Kernel 5/6: reduce 65 position-chunk partials -> atten  (verified)
// ---------------------------------------------------------------------------
__global__ __launch_bounds__(256) void reduce_att(
    const float* __restrict__ apart, float* __restrict__ atten)
{
  int idx = blockIdx.x * 256 + threadIdx.x;   // grid 256 -> 65536
  float s = 0.f;
  for (int c = 0; c < 65; ++c) s += apart[(size_t)c * 65536 + idx];
  atten[idx] = s;
}

// ---------------------------------------------------------------------------
extern "C" void kernel_launch(void* const* d_in, const int* in_sizes, int n_in,
                              void* d_out, int out_size, void* d_ws, size_t ws_size,
                              hipStream_t stream) {
  const float* x       = (const float*)d_in[0];
  // d_in[1] = start_pos (fixed 4096, baked into constants)
  const float* mask    = (const float*)d_in[2];
  const float* Wq      = (const float*)d_in[3];
  const float* Wk      = (const float*)d_in[4];
  const float* Wv      = (const float*)d_in[5];
  const float* Wo      = (const float*)d_in[6];
  const float* cache_k = (const float*)d_in[7];
  const float* cache_v = (const float*)d_in[8];
  float* out    = (float*)d_out;           // [8,16,512]
  float* weight = out + 65536;             // [8,16,4112]
  float* ws     = (float*)d_ws;

  // q/k/v projections, full-K (1536 concat cols, 32 per block)
  proj_dot<<<dim3(8, 48), 256, 0, stream>>>(
      x, Wq, Wk, Wv, ws + QBUF, ws + KNEW, ws + VNEW);
  // scores -> weight output (pre-mask, scaled)
  scores_kernel<<<dim3(8, 65), 256, 0, stream>>>(ws + QBUF, cache_k, ws + KNEW, weight);
  // softmax(weight + mask) -> probs
  softmax_kernel<<<dim3(128), 256, 0, stream>>>(weight, mask, ws + PROBS);
  // probs @ v_full (split over position chunks)
  attnv_kernel<<<dim3(8, 65), 256, 0, stream>>>(ws + PROBS, cache_v, ws + VNEW, ws + APART);
  reduce_att<<<dim3(256), 256, 0, stream>>>(ws + APART, ws + ATTEN);
  // output projection (512 cols, 32 per block; m==0 always)
  proj_dot<<<dim3(8, 16), 256, 0, stream>>>(
      ws + ATTEN, Wo, Wo, Wo, out, out, out);
}

// Round 6
// 301.114 us; speedup vs baseline: 1.0733x; 1.0296x over previous
//
#include <hip/hip_runtime.h>

#define BSZ 8
#define SEQ 16
#define DIMN 512
#define SP 4096
#define KVL 4112

#define SCALE 0.0625f   // (512/2)^-0.5

// workspace layout (float offsets)
#define QBUF  0          // 65536
#define KNEW  65536      // 65536
#define VNEW  131072     // 65536
#define MLBUF 196608     // 2 * 65 * 128 = 16640  (m plane, then l plane)
#define APART 213248     // 65 * 65536 = 4259840
#define ATTEN 4473088    // 65536

#define MLSTRIDE 8320    // 65 * 128

// ---------------------------------------------------------------------------
// 16-value cross-lane tree reduction (ownership halving). Each lane enters
// with acc[16] = partial dots over its 8 k-elements; lanes 0..15 exit with
// the full dot for row s = bitrev4(lane). Verified in scores/proj kernels.
// ---------------------------------------------------------------------------
__device__ __forceinline__ float tree16(const float* acc, bool b1, bool b2, bool b4, bool b8)
{
  float r8[8];
#pragma unroll
  for (int u = 0; u < 8; ++u) {
    float keep = b1 ? acc[u + 8] : acc[u];
    float send = b1 ? acc[u] : acc[u + 8];
    r8[u] = keep + __shfl_xor(send, 1);
  }
  float r4[4];
#pragma unroll
  for (int u = 0; u < 4; ++u) {
    float keep = b2 ? r8[u + 4] : r8[u];
    float send = b2 ? r8[u] : r8[u + 4];
    r4[u] = keep + __shfl_xor(send, 2);
  }
  float r2[2];
#pragma unroll
  for (int u = 0; u < 2; ++u) {
    float keep = b4 ? r4[u + 2] : r4[u];
    float send = b4 ? r4[u] : r4[u + 2];
    r2[u] = keep + __shfl_xor(send, 4);
  }
  float keep = b8 ? r2[1] : r2[0];
  float send = b8 ? r2[0] : r2[1];
  float r1 = keep + __shfl_xor(send, 8);
  r1 += __shfl_xor(r1, 16);
  r1 += __shfl_xor(r1, 32);
  return r1;
}

// ---------------------------------------------------------------------------
// Kernel 1/4: projection, dot-product style (verified R5).
// grid (8 b, ncols/32), block 256.  Wave w handles cols e0 + w + 4*i.
// ---------------------------------------------------------------------------
__global__ __launch_bounds__(256) void proj_dot(
    const float* __restrict__ X,
    const float* __restrict__ W0, const float* __restrict__ W1,
    const float* __restrict__ W2,
    float* __restrict__ D0, float* __restrict__ D1, float* __restrict__ D2)
{
  int b = blockIdx.x;
  int e0 = blockIdx.y * 32;
  int t = threadIdx.x, lane = t & 63, w = t >> 6;

  float4 xa[SEQ], xb[SEQ];
  const float* xbase = X + (size_t)b * SEQ * DIMN + lane * 8;
#pragma unroll
  for (int s = 0; s < SEQ; ++s) {
    xa[s] = *(const float4*)(xbase + s * DIMN);
    xb[s] = *(const float4*)(xbase + s * DIMN + 4);
  }

  bool b1 = (lane & 1), b2 = (lane & 2), b4 = (lane & 4), b8 = (lane & 8);
#pragma unroll 2
  for (int i = 0; i < 8; ++i) {
    int e = e0 + w + 4 * i;              // wave-uniform
    int m = e >> 9, col = e & 511;
    const float* W = (m == 0) ? W0 : (m == 1) ? W1 : W2;
    const float* wrow = W + (size_t)col * DIMN + lane * 8;
    float4 ka = *(const float4*)(wrow);
    float4 kb = *(const float4*)(wrow + 4);

    float acc[SEQ];
#pragma unroll
    for (int s = 0; s < SEQ; ++s) {
      acc[s] = xa[s].x * ka.x + xa[s].y * ka.y + xa[s].z * ka.z + xa[s].w * ka.w
             + xb[s].x * kb.x + xb[s].y * kb.y + xb[s].z * kb.z + xb[s].w * kb.w;
    }
    float r1 = tree16(acc, b1, b2, b4, b8);
    if (lane < 16) {
      int s = ((lane & 1) << 3) | ((lane & 2) << 1) | ((lane & 4) >> 1) | ((lane & 8) >> 3);
      float* D = (m == 0) ? D0 : (m == 1) ? D1 : D2;
      D[(size_t)(b * SEQ + s) * DIMN + col] = r1;
    }
  }
}

// ---------------------------------------------------------------------------
// Kernel 2/4: fused flash attention chunk.  grid (8, 65), block 256.
// Phase 1 = verified scores loop (writes weight + raw scaled score to LDS).
// Phase 2 = per-chunk softmax stats: row max m_r / sum l_r over 64 positions,
//           LDS becomes unnormalized exp weights.
// Phase 3 = verified attnv PV loop -> apart partial; {m,l} -> mlbuf.
// ---------------------------------------------------------------------------
__global__ __launch_bounds__(256) void fused_attn(
    const float* __restrict__ qbuf, const float* __restrict__ cache_k,
    const float* __restrict__ knew, const float* __restrict__ mask,
    const float* __restrict__ cache_v, const float* __restrict__ vnew,
    float* __restrict__ weight, float* __restrict__ apart,
    float* __restrict__ mlbuf)
{
  __shared__ float pl[SEQ][64];
  __shared__ float lm[SEQ], ll[SEQ];
  int b = blockIdx.x, c = blockIdx.y;
  int p0 = c * 64;
  int len = KVL - p0; if (len > 64) len = 64;
  int t = threadIdx.x, lane = t & 63, w = t >> 6;

  // ---- phase 1: scores (identical math to verified scores_kernel) ----
  {
    float4 qa[SEQ], qb[SEQ];
    const float* qbase = qbuf + (size_t)b * SEQ * DIMN + lane * 8;
#pragma unroll
    for (int s = 0; s < SEQ; ++s) {
      qa[s] = *(const float4*)(qbase + s * DIMN);
      qb[s] = *(const float4*)(qbase + s * DIMN + 4);
    }
    bool b1 = (lane & 1), b2 = (lane & 2), b4 = (lane & 4), b8 = (lane & 8);
    int niter = (len - w + 3) >> 2;   // positions p0 + w + 4*i
#pragma unroll 2
    for (int i = 0; i < niter; ++i) {
      int p = p0 + w + 4 * i;
      const float* krow = (p < SP)
          ? (cache_k + ((size_t)b * 8192 + p) * DIMN)
          : (knew + (size_t)(b * SEQ + (p - SP)) * DIMN);
      float4 ka = *(const float4*)(krow + lane * 8);
      float4 kb = *(const float4*)(krow + lane * 8 + 4);

      float acc[SEQ];
#pragma unroll
      for (int s = 0; s < SEQ; ++s) {
        acc[s] = qa[s].x * ka.x + qa[s].y * ka.y + qa[s].z * ka.z + qa[s].w * ka.w
               + qb[s].x * kb.x + qb[s].y * kb.y + qb[s].z * kb.z + qb[s].w * kb.w;
      }
      float r1 = tree16(acc, b1, b2, b4, b8);
      if (lane < 16) {
        int s = ((lane & 1) << 3) | ((lane & 2) << 1) | ((lane & 4) >> 1) | ((lane & 8) >> 3);
        float sc = r1 * SCALE;
        weight[(size_t)(b * SEQ + s) * KVL + p] = sc;
        pl[s][p - p0] = sc;
      }
    }
  }
  __syncthreads();

  // ---- phase 2: per-chunk softmax stats.  16 threads per row, 4 pos each.
  // Row r's threads are a contiguous 16-lane group within one wave.
  {
    int r = t >> 4, j0 = (t & 15) * 4;
    float v[4];
#pragma unroll
    for (int k = 0; k < 4; ++k) {
      int j = j0 + k;
      v[k] = (j < len) ? pl[r][j] + mask[r * KVL + p0 + j] : -1e30f;
    }
    float m = fmaxf(fmaxf(v[0], v[1]), fmaxf(v[2], v[3]));
    m = fmaxf(m, __shfl_xor(m, 1));
    m = fmaxf(m, __shfl_xor(m, 2));
    m = fmaxf(m, __shfl_xor(m, 4));
    m = fmaxf(m, __shfl_xor(m, 8));
    float e[4], sum = 0.f;
#pragma unroll
    for (int k = 0; k < 4; ++k) { e[k] = __expf(v[k] - m); sum += e[k]; }
    sum += __shfl_xor(sum, 1);
    sum += __shfl_xor(sum, 2);
    sum += __shfl_xor(sum, 4);
    sum += __shfl_xor(sum, 8);
#pragma unroll
    for (int k = 0; k < 4; ++k) pl[r][j0 + k] = e[k];
    if ((t & 15) == 0) { lm[r] = m; ll[r] = sum; }
  }
  __syncthreads();

  // ---- phase 3: PV partial (identical loop to verified attnv_kernel) ----
  float acc0[SEQ], acc1[SEQ];
#pragma unroll
  for (int q = 0; q < SEQ; ++q) { acc0[q] = 0.f; acc1[q] = 0.f; }

  int nj4 = len >> 2;   // 16 or 4
  for (int j4 = 0; j4 < nj4; ++j4) {
    float4 pv[SEQ];
#pragma unroll
    for (int q = 0; q < SEQ; ++q) pv[q] = *(const float4*)&pl[q][j4 * 4];
#pragma unroll
    for (int jj = 0; jj < 4; ++jj) {
      int p = p0 + j4 * 4 + jj;
      const float* vrow = (p < SP)
          ? (cache_v + ((size_t)b * 8192 + p) * DIMN)
          : (vnew + (size_t)(b * SEQ + (p - SP)) * DIMN);
      float va = vrow[t], vb = vrow[t + 256];
#pragma unroll
      for (int q = 0; q < SEQ; ++q) {
        float pj = (jj == 0) ? pv[q].x : (jj == 1) ? pv[q].y : (jj == 2) ? pv[q].z : pv[q].w;
        acc0[q] += pj * va;
        acc1[q] += pj * vb;
      }
    }
  }
  float* outp = apart + (size_t)c * 65536 + (size_t)b * SEQ * DIMN;
#pragma unroll
  for (int q = 0; q < SEQ; ++q) {
    outp[q * DIMN + t] = acc0[q];
    outp[q * DIMN + t + 256] = acc1[q];
  }
  if (t < SEQ) {
    mlbuf[c * 128 + b * SEQ + t] = lm[t];
    mlbuf[MLSTRIDE + c * 128 + b * SEQ + t] = ll[t];
  }
}

// ---------------------------------------------------------------------------
// Kernel 3/4: flash recombination.  grid (256 = 128 rows x 2 halves), blk 256.
// out[row][col] = sum_c exp(m_c - M) * pv_c[row][col] / sum_c exp(m_c - M) l_c
// ---------------------------------------------------------------------------
__global__ __launch_bounds__(256) void flash_reduce(
    const float* __restrict__ apart, const float* __restrict__ mlbuf,
    float* __restrict__ atten)
{
  __shared__ float msh[65], lsh[65], wfac[65];
  int row = blockIdx.x >> 1, half = blockIdx.x & 1;
  int t = threadIdx.x;

  if (t < 65) {
    msh[t] = mlbuf[t * 128 + row];
    lsh[t] = mlbuf[MLSTRIDE + t * 128 + row];
  }
  __syncthreads();

  float M = -1e30f;
  for (int c = 0; c < 65; ++c) M = fmaxf(M, msh[c]);
  if (t < 65) wfac[t] = __expf(msh[t] - M);
  __syncthreads();

  float L = 0.f;
  for (int c = 0; c < 65; ++c) L += wfac[c] * lsh[c];
  float inv = 1.0f / L;

  int col = half * 256 + t;
  const float* src = apart + (size_t)row * DIMN + col;
  float s = 0.f;
  for (int c = 0; c < 65; ++c) s += wfac[c] * src[(size_t)c * 65536];
  atten[(size_t)row * DIMN + col] = s * inv;
}

// ---------------------------------------------------------------------------
extern "C" void kernel_launch(void* const* d_in, const int* in_sizes, int n_in,
                              void* d_out, int out_size, void* d_ws, size_t ws_size,
                              hipStream_t stream) {
  const float* x       = (const float*)d_in[0];
  // d_in[1] = start_pos (fixed 4096, baked into constants)
  const float* mask    = (const float*)d_in[2];
  const float* Wq      = (const float*)d_in[3];
  const float* Wk      = (const float*)d_in[4];
  const float* Wv      = (const float*)d_in[5];
  const float* Wo      = (const float*)d_in[6];
  const float* cache_k = (const float*)d_in[7];
  const float* cache_v = (const float*)d_in[8];
  float* out    = (float*)d_out;           // [8,16,512]
  float* weight = out + 65536;             // [8,16,4112]
  float* ws     = (float*)d_ws;

  // q/k/v projections, full-K (1536 concat cols, 32 per block)
  proj_dot<<<dim3(8, 48), 256, 0, stream>>>(
      x, Wq, Wk, Wv, ws + QBUF, ws + KNEW, ws + VNEW);
  // fused scores + weight output + chunk softmax + PV partials
  fused_attn<<<dim3(8, 65), 256, 0, stream>>>(
      ws + QBUF, cache_k, ws + KNEW, mask, cache_v, ws + VNEW,
      weight, ws + APART, ws + MLBUF);
  // recombine 65 chunk partials with softmax rescale
  flash_reduce<<<dim3(256), 256, 0, stream>>>(
      ws + APART, ws + MLBUF, ws + ATTEN);
  // output projection (512 cols, 32 per block; m==0 always)
  proj_dot<<<dim3(8, 16), 256, 0, stream>>>(
      ws + ATTEN, Wo, Wo, Wo, out, out, out);
}